// Round 1
// baseline (253.267 us; speedup 1.0000x reference)
//
#include <hip/hip_runtime.h>

typedef __attribute__((ext_vector_type(8))) short s16x8;   // 8 bf16 (4 VGPRs) MFMA A/B frag
typedef __attribute__((ext_vector_type(4))) short s16x4;
typedef __attribute__((ext_vector_type(4))) float f32x4;   // MFMA C/D frag

#define ST 72  // LDS row stride in bf16 elements: 144 B = 16-B aligned, odd multiple of 8

__device__ __forceinline__ short f2bf(float f) {
    unsigned u = __builtin_bit_cast(unsigned, f);
    u += 0x7FFFu + ((u >> 16) & 1u);   // round-to-nearest-even
    return (short)(u >> 16);
}

__global__ __launch_bounds__(256, 3) void sam3e_fused(
    const float* __restrict__ F, const float* __restrict__ Kw,
    const float* __restrict__ Qw, float* __restrict__ out)
{
    __shared__ __align__(16) short sKw[64 * ST];
    __shared__ __align__(16) short sQw[64 * ST];
    __shared__ __align__(16) short sA [64 * ST];
    __shared__ __align__(16) short sAT[64 * ST];
    __shared__ __align__(16) short sKS[64 * ST];   // KF, then S

    const int b    = blockIdx.x;
    const int tid  = threadIdx.x;
    const int wave = tid >> 6;
    const int lane = tid & 63;
    const int col  = lane & 15;
    const int quad = lane >> 4;

    // ---- stage weights fp32 -> bf16 (row-major [e][d]) ----
    const f32x4* Kv = (const f32x4*)Kw;
    const f32x4* Qv = (const f32x4*)Qw;
    #pragma unroll
    for (int i = tid; i < 1024; i += 256) {
        int e = i >> 4, d4 = (i & 15) << 2;
        f32x4 kv = Kv[i], qv = Qv[i];
        s16x4 hk = { f2bf(kv.x), f2bf(kv.y), f2bf(kv.z), f2bf(kv.w) };
        s16x4 hq = { f2bf(qv.x), f2bf(qv.y), f2bf(qv.z), f2bf(qv.w) };
        *(s16x4*)&sKw[e * ST + d4] = hk;
        *(s16x4*)&sQw[e * ST + d4] = hq;
    }

    // ---- stage A (rows 50..63 zero-padded) + transposed copy ----
    const f32x4* Fv = (const f32x4*)(F + (size_t)b * 3200);
    const f32x4 zero4 = {0.f, 0.f, 0.f, 0.f};
    #pragma unroll
    for (int i = tid; i < 1024; i += 256) {
        int n = i >> 4, d4 = (i & 15) << 2;
        f32x4 v = (n < 50) ? Fv[i] : zero4;
        s16x4 h = { f2bf(v.x), f2bf(v.y), f2bf(v.z), f2bf(v.w) };
        *(s16x4*)&sA[n * ST + d4] = h;
        sAT[(d4 + 0) * ST + n] = h.x;
        sAT[(d4 + 1) * ST + n] = h.y;
        sAT[(d4 + 2) * ST + n] = h.z;
        sAT[(d4 + 3) * ST + n] = h.w;
    }
    __syncthreads();

    const int mt   = wave;                    // each wave owns rows [16mt, 16mt+16)
    const int arow = (mt * 16 + col) * ST;

    // A-operand frags for rows mt (reused by step 1, step 2, Q-branch)
    s16x8 a0 = *(const s16x8*)&sA[arow + quad * 8];
    s16x8 a1 = *(const s16x8*)&sA[arow + 32 + quad * 8];

    // ---- step 1: KF = A @ Kw^T -> sKS (bf16) ----
    #pragma unroll
    for (int nt = 0; nt < 4; ++nt) {
        const int brow = (nt * 16 + col) * ST;
        s16x8 b0 = *(const s16x8*)&sKw[brow + quad * 8];
        s16x8 b1 = *(const s16x8*)&sKw[brow + 32 + quad * 8];
        f32x4 acc = {0.f, 0.f, 0.f, 0.f};
        acc = __builtin_amdgcn_mfma_f32_16x16x32_bf16(a0, b0, acc, 0, 0, 0);
        acc = __builtin_amdgcn_mfma_f32_16x16x32_bf16(a1, b1, acc, 0, 0, 0);
        #pragma unroll
        for (int r = 0; r < 4; ++r)
            sKS[(mt * 16 + quad * 4 + r) * ST + nt * 16 + col] = f2bf(acc[r]);
    }
    __syncthreads();

    // ---- step 2: S = A @ KF^T (regs), then overwrite sKS with S ----
    f32x4 Sacc[4];
    #pragma unroll
    for (int nt = 0; nt < 4; ++nt) {
        const int brow = (nt * 16 + col) * ST;
        s16x8 b0 = *(const s16x8*)&sKS[brow + quad * 8];
        s16x8 b1 = *(const s16x8*)&sKS[brow + 32 + quad * 8];
        f32x4 acc = {0.f, 0.f, 0.f, 0.f};
        acc = __builtin_amdgcn_mfma_f32_16x16x32_bf16(a0, b0, acc, 0, 0, 0);
        acc = __builtin_amdgcn_mfma_f32_16x16x32_bf16(a1, b1, acc, 0, 0, 0);
        Sacc[nt] = acc;
    }
    __syncthreads();
    #pragma unroll
    for (int nt = 0; nt < 4; ++nt)
        #pragma unroll
        for (int r = 0; r < 4; ++r)
            sKS[(mt * 16 + quad * 4 + r) * ST + nt * 16 + col] = f2bf(Sacc[nt][r]);
    __syncthreads();

    // ---- step 3: T = S @ A, Qt = A @ Qw^T, out = F*T + Qt ----
    s16x8 sa0 = *(const s16x8*)&sKS[arow + quad * 8];
    s16x8 sa1 = *(const s16x8*)&sKS[arow + 32 + quad * 8];
    const float* Fb = F   + (size_t)b * 3200;
    float*       Ob = out + (size_t)b * 3200;
    #pragma unroll
    for (int nt = 0; nt < 4; ++nt) {
        const int brow = (nt * 16 + col) * ST;
        s16x8 bt0 = *(const s16x8*)&sAT[brow + quad * 8];
        s16x8 bt1 = *(const s16x8*)&sAT[brow + 32 + quad * 8];
        s16x8 bq0 = *(const s16x8*)&sQw[brow + quad * 8];
        s16x8 bq1 = *(const s16x8*)&sQw[brow + 32 + quad * 8];
        f32x4 t = {0.f, 0.f, 0.f, 0.f};
        f32x4 q = {0.f, 0.f, 0.f, 0.f};
        t = __builtin_amdgcn_mfma_f32_16x16x32_bf16(sa0, bt0, t, 0, 0, 0);
        t = __builtin_amdgcn_mfma_f32_16x16x32_bf16(sa1, bt1, t, 0, 0, 0);
        q = __builtin_amdgcn_mfma_f32_16x16x32_bf16(a0,  bq0, q, 0, 0, 0);
        q = __builtin_amdgcn_mfma_f32_16x16x32_bf16(a1,  bq1, q, 0, 0, 0);
        #pragma unroll
        for (int r = 0; r < 4; ++r) {
            int n = mt * 16 + quad * 4 + r;
            if (n < 50) {
                int idx = n * 64 + nt * 16 + col;
                Ob[idx] = Fb[idx] * t[r] + q[r];
            }
        }
    }
}

extern "C" void kernel_launch(void* const* d_in, const int* in_sizes, int n_in,
                              void* d_out, int out_size, void* d_ws, size_t ws_size,
                              hipStream_t stream) {
    const float* F  = (const float*)d_in[0];   // [8192,50,64]
    const float* Kw = (const float*)d_in[1];   // [64,64]
    const float* Qw = (const float*)d_in[2];   // [64,64]
    float* out = (float*)d_out;                // [8192,50,64]
    sam3e_fused<<<8192, 256, 0, stream>>>(F, Kw, Qw, out);
}

// Round 2
// 221.470 us; speedup vs baseline: 1.1436x; 1.1436x over previous
//
#include <hip/hip_runtime.h>

typedef __attribute__((ext_vector_type(8))) short s16x8;   // 8 bf16 MFMA A/B frag
typedef __attribute__((ext_vector_type(4))) short s16x4;
typedef __attribute__((ext_vector_type(4))) float f32x4;   // MFMA C/D frag

#define ST 72   // LDS row stride (shorts): 144 B = 16B-aligned, bank step 36%32=4 -> 2-way (free)
#define NB 8    // batches per block; grid = 8192/NB = 1024 = 4 blocks/CU exactly
#define MFMA __builtin_amdgcn_mfma_f32_16x16x32_bf16

__device__ __forceinline__ short f2bf(float f) {
    unsigned u = __builtin_bit_cast(unsigned, f);
    u += 0x7FFFu + ((u >> 16) & 1u);   // RTNE
    return (short)(u >> 16);
}
__device__ __forceinline__ s16x8 cvt8(f32x4 a, f32x4 b) {
    s16x8 r = { f2bf(a.x), f2bf(a.y), f2bf(a.z), f2bf(a.w),
                f2bf(b.x), f2bf(b.y), f2bf(b.z), f2bf(b.w) };
    return r;
}

__global__ __launch_bounds__(256, 4) void sam3e_v2(
    const float* __restrict__ F, const float* __restrict__ Kw,
    const float* __restrict__ Qw, float* __restrict__ out)
{
    __shared__ __align__(16) short sKw[64 * ST];   // K row-major bf16
    __shared__ __align__(16) short sQw[64 * ST];   // Q row-major bf16
    __shared__ __align__(16) short sAT[64 * ST];   // A^T bf16 (cols n, zero-padded n>=50)
    __shared__ __align__(16) short sKS[64 * ST];   // KF, then overwritten with S

    const int tid  = threadIdx.x;
    const int w    = tid >> 6;      // wave id = row-tile mt
    const int lane = tid & 63;
    const int col  = lane & 15;
    const int q    = lane >> 4;

    // ---- stage weights once (row-major; no transpose needed: Y-operand = W rows) ----
    {
        const int e  = tid & 63;
        const int dg = tid >> 6;
        const f32x4* Kv = (const f32x4*)(Kw + e * 64 + dg * 16);
        const f32x4* Qv = (const f32x4*)(Qw + e * 64 + dg * 16);
        #pragma unroll
        for (int k = 0; k < 4; ++k) {
            f32x4 kv = Kv[k], qv = Qv[k];
            s16x4 hk = { f2bf(kv.x), f2bf(kv.y), f2bf(kv.z), f2bf(kv.w) };
            s16x4 hq = { f2bf(qv.x), f2bf(qv.y), f2bf(qv.z), f2bf(qv.w) };
            *(s16x4*)&sKw[e * ST + dg * 16 + k * 4] = hk;
            *(s16x4*)&sQw[e * ST + dg * 16 + k * 4] = hq;
        }
    }

    const int sn  = tid & 63;   // staging: this thread owns column n of A^T
    const int sdg = tid >> 6;   // and d-rows [16*sdg, 16*sdg+16)
    const f32x4 z4 = {0.f, 0.f, 0.f, 0.f};

    int b = blockIdx.x * NB;
    // prefetch batch 0 of this block
    f32x4 pf0 = z4, pf1 = z4, pf2 = z4, pf3 = z4;
    if (sn < 50) {
        const f32x4* Fr = (const f32x4*)(F + (size_t)b * 3200 + sn * 64 + sdg * 16);
        pf0 = Fr[0]; pf1 = Fr[1]; pf2 = Fr[2]; pf3 = Fr[3];
    }

    for (int it = 0; it < NB; ++it, ++b) {
        const float* Fb = F   + (size_t)b * 3200;
        float*       Ob = out + (size_t)b * 3200;

        __syncthreads();   // b1: prev iter's readers of sAT/sKS done (covers weight staging at it=0)

        // ---- stage A^T from prefetch regs: lanes write consecutive n -> conflict-free ----
        {
            const int d0 = sdg * 16;
            short h[16] = { f2bf(pf0.x), f2bf(pf0.y), f2bf(pf0.z), f2bf(pf0.w),
                            f2bf(pf1.x), f2bf(pf1.y), f2bf(pf1.z), f2bf(pf1.w),
                            f2bf(pf2.x), f2bf(pf2.y), f2bf(pf2.z), f2bf(pf2.w),
                            f2bf(pf3.x), f2bf(pf3.y), f2bf(pf3.z), f2bf(pf3.w) };
            #pragma unroll
            for (int i = 0; i < 16; ++i) sAT[(d0 + i) * ST + sn] = h[i];
        }

        // ---- A-row frags for this wave's row-tile, direct from global (L2-hot via prefetch) ----
        s16x8 a0, a1;
        {
            const int row = 16 * w + col;
            f32x4 v0 = z4, v1 = z4, v2 = z4, v3 = z4;
            if (row < 50) {
                const f32x4* Fr = (const f32x4*)(Fb + row * 64);
                v0 = Fr[2 * q]; v1 = Fr[2 * q + 1];       // d = q*8..q*8+7
                v2 = Fr[8 + 2 * q]; v3 = Fr[8 + 2 * q + 1]; // d = 32+q*8..
            }
            a0 = cvt8(v0, v1); a1 = cvt8(v2, v3);
        }

        // ---- step 1: KF = A @ K^T -> sKS (row-major [n][e]) ----
        #pragma unroll
        for (int nt = 0; nt < 4; ++nt) {
            const short* yb = &sKw[(16 * nt + col) * ST + 8 * q];
            f32x4 acc = {0.f, 0.f, 0.f, 0.f};
            acc = MFMA(a0, *(const s16x8*)yb,        acc, 0, 0, 0);
            acc = MFMA(a1, *(const s16x8*)(yb + 32), acc, 0, 0, 0);
            #pragma unroll
            for (int r = 0; r < 4; ++r)
                sKS[(16 * w + 4 * q + r) * ST + 16 * nt + col] = f2bf(acc[r]);
        }
        __syncthreads();   // b2: KF visible (also orders sAT writes before step-3 reads)

        // ---- step 2: S = A @ KF^T (held in regs) ----
        f32x4 S[4];
        #pragma unroll
        for (int nt = 0; nt < 4; ++nt) {
            const short* yb = &sKS[(16 * nt + col) * ST + 8 * q];
            f32x4 acc = {0.f, 0.f, 0.f, 0.f};
            acc = MFMA(a0, *(const s16x8*)yb,        acc, 0, 0, 0);
            acc = MFMA(a1, *(const s16x8*)(yb + 32), acc, 0, 0, 0);
            S[nt] = acc;
        }

        // ---- prefetch next batch's F while everyone drains step 2 ----
        if (it + 1 < NB && sn < 50) {
            const f32x4* Fr = (const f32x4*)(Fb + 3200 + sn * 64 + sdg * 16);
            pf0 = Fr[0]; pf1 = Fr[1]; pf2 = Fr[2]; pf3 = Fr[3];
        }

        __syncthreads();   // b3: all KF reads done
        #pragma unroll
        for (int nt = 0; nt < 4; ++nt)
            #pragma unroll
            for (int r = 0; r < 4; ++r)
                sKS[(16 * w + 4 * q + r) * ST + 16 * nt + col] = f2bf(S[nt][r]);
        __syncthreads();   // b4: S visible

        // ---- step 3: T = S @ A (Y = A^T rows), Q = A @ Q^T; epilogue fused ----
        const short* sb = &sKS[(16 * w + col) * ST + 8 * q];
        s16x8 s0 = *(const s16x8*)sb;
        s16x8 s1 = *(const s16x8*)(sb + 32);
        #pragma unroll
        for (int nt = 0; nt < 4; ++nt) {
            const short* tb = &sAT[(16 * nt + col) * ST + 8 * q];
            const short* qb = &sQw[(16 * nt + col) * ST + 8 * q];
            f32x4 t  = {0.f, 0.f, 0.f, 0.f};
            f32x4 qa = {0.f, 0.f, 0.f, 0.f};
            t  = MFMA(s0, *(const s16x8*)tb,        t,  0, 0, 0);
            t  = MFMA(s1, *(const s16x8*)(tb + 32), t,  0, 0, 0);
            qa = MFMA(a0, *(const s16x8*)qb,        qa, 0, 0, 0);
            qa = MFMA(a1, *(const s16x8*)(qb + 32), qa, 0, 0, 0);
            #pragma unroll
            for (int r = 0; r < 4; ++r) {
                const int n = 16 * w + 4 * q + r;
                if (n < 50) {
                    const int idx = n * 64 + 16 * nt + col;
                    Ob[idx] = Fb[idx] * t[r] + qa[r];
                }
            }
        }
    }
}

extern "C" void kernel_launch(void* const* d_in, const int* in_sizes, int n_in,
                              void* d_out, int out_size, void* d_ws, size_t ws_size,
                              hipStream_t stream) {
    const float* F  = (const float*)d_in[0];   // [8192,50,64]
    const float* Kw = (const float*)d_in[1];   // [64,64]
    const float* Qw = (const float*)d_in[2];   // [64,64]
    float* out = (float*)d_out;
    sam3e_v2<<<8192 / NB, 256, 0, stream>>>(F, Kw, Qw, out);
}